// Round 1
// baseline (178.309 us; speedup 1.0000x reference)
//
#include <hip/hip_runtime.h>

// Problem constants (match reference)
constexpr int B = 32, N = 256, C = 3, H = 512, W = 512, K = 32;
constexpr int OUT_FLOAT4 = B * N * C * K * K / 4;  // 6,291,456

__global__ __launch_bounds__(256) void rgte_kernel(
    const float* __restrict__ img,
    const int*   __restrict__ mu,
    const float* __restrict__ gauss,
    float*       __restrict__ out)
{
    int tid4 = blockIdx.x * blockDim.x + threadIdx.x;  // one output float4
    if (tid4 >= OUT_FLOAT4) return;

    // Decompose: out flat float4 index -> (bn, c, ky, kx4)
    int kx4  = tid4 & 7;           // 8 float4 per K-row (K=32)
    int ky   = (tid4 >> 3) & 31;   // K rows
    int rem  = tid4 >> 8;          // global channel index = bn*C + c (K*K/4 = 256)
    int c    = rem % 3;
    int bn   = rem / 3;            // b*N + n
    int b    = bn >> 8;            // N = 256

    int mu0 = mu[2 * bn];
    int mu1 = mu[2 * bn + 1];

    const float* src = img + (((b * C + c) * H + mu0 + ky) * W + mu1 + kx4 * 4);

    // Gaussian row chunk is 16B-aligned -> vector load (tiny, cache-resident)
    float4 g = *reinterpret_cast<const float4*>(gauss + ky * K + kx4 * 4);

    float4 o;
    o.x = src[0] * g.x;
    o.y = src[1] * g.y;
    o.z = src[2] * g.z;
    o.w = src[3] * g.w;

    reinterpret_cast<float4*>(out)[tid4] = o;
}

extern "C" void kernel_launch(void* const* d_in, const int* in_sizes, int n_in,
                              void* d_out, int out_size, void* d_ws, size_t ws_size,
                              hipStream_t stream) {
    const float* img   = (const float*)d_in[0];
    const int*   mu    = (const int*)d_in[1];
    const float* gauss = (const float*)d_in[2];
    float*       out   = (float*)d_out;

    int blocks = OUT_FLOAT4 / 256;  // 24576, exact
    rgte_kernel<<<blocks, 256, 0, stream>>>(img, mu, gauss, out);
}

// Round 3
// 175.034 us; speedup vs baseline: 1.0187x; 1.0187x over previous
//
#include <hip/hip_runtime.h>

// Problem constants (match reference)
constexpr int B = 32, N = 256, C = 3, H = 512, W = 512, K = 32;

typedef float f32x4 __attribute__((ext_vector_type(4)));

// Block = 256 threads = one (bn, c) cell: 32 rows x 8 float4-chunks.
// All patch parameters (bn, c, mu) are block-uniform -> scalar regs + s_load.
__global__ __launch_bounds__(256) void rgte_kernel(
    const float* __restrict__ img,
    const int*   __restrict__ mu,
    const float* __restrict__ gauss,
    float*       __restrict__ out)
{
    const int rem = blockIdx.x;   // = bn*C + c   (grid = B*N*C = 24576)
    const int c   = rem % 3;
    const int bn  = rem / 3;      // b*N + n
    const int b   = bn >> 8;      // N = 256

    // Block-uniform: compiler keeps these in SGPRs, mu via s_load.
    const int mu0 = mu[2 * bn];
    const int mu1 = mu[2 * bn + 1];
    const float* patch_base = img + (((b * C + c) * H + mu0) * W + mu1);

    const int local = threadIdx.x;
    const int kx4   = local & 7;   // 8 float4 per K-row
    const int ky    = local >> 3;  // 32 rows

    // One (possibly 4B-aligned-only) 16B load — gfx9+ global HW handles
    // unaligned dwordx4.
    f32x4 v = *reinterpret_cast<const f32x4*>(patch_base + ky * W + kx4 * 4);

    // Gaussian chunk is 16B-aligned and L1-resident (4 KB total).
    f32x4 g = *reinterpret_cast<const f32x4*>(gauss + ky * K + kx4 * 4);

    f32x4 o = v * g;

    // Streaming output: nontemporal to avoid evicting the 12.6 MB image
    // from L2 with the 100.7 MB write.
    f32x4* out4 = reinterpret_cast<f32x4*>(out) + (blockIdx.x * 256 + local);
    __builtin_nontemporal_store(o, out4);
}

extern "C" void kernel_launch(void* const* d_in, const int* in_sizes, int n_in,
                              void* d_out, int out_size, void* d_ws, size_t ws_size,
                              hipStream_t stream) {
    const float* img   = (const float*)d_in[0];
    const int*   mu    = (const int*)d_in[1];
    const float* gauss = (const float*)d_in[2];
    float*       out   = (float*)d_out;

    rgte_kernel<<<B * N * C, 256, 0, stream>>>(img, mu, gauss, out);
}